// Round 2
// baseline (906.039 us; speedup 1.0000x reference)
//
#include <hip/hip_runtime.h>
#include <stdint.h>

// Problem constants
#define B_ 2
#define N_ 25
#define S_ 4096
#define I_ 63
#define W_ 256
#define D_ 8
#define Z_ 16

typedef float f32x4 __attribute__((ext_vector_type(4)));
typedef __bf16 bf16x8 __attribute__((ext_vector_type(8)));

// ---- bf16 split helpers (RNE) ----
__device__ __forceinline__ unsigned short f2bf(float x) {
  unsigned int u = __float_as_uint(x);
  unsigned int r = (u + 0x7fffu + ((u >> 16) & 1u)) >> 16;
  return (unsigned short)r;
}
__device__ __forceinline__ float bf2f(unsigned short h) {
  return __uint_as_float(((unsigned int)h) << 16);
}

// =====================================================================
// Prep: transpose [K][V] -> [V][Kp] (k-contiguous rows), split fp32 into
// bf16 hi/lo. in: [nmat][K][V]; out_hi/out_lo: [nmat][V][Kp]. Zero-pads
// k in [K,Kp).
// =====================================================================
__global__ void prep_tr(const float* __restrict__ in,
                        unsigned short* __restrict__ oh,
                        unsigned short* __restrict__ ol,
                        int K, int V, int Kp, int tiles_k, int tiles_v) {
  __shared__ float tile[64][65];
  int tpm = tiles_k * tiles_v;
  int m  = blockIdx.x / tpm;
  int tt = blockIdx.x - m * tpm;
  int tk = tt / tiles_v, tv = tt - tk * tiles_v;
  int k0 = tk * 64, v0 = tv * 64;
  const float* src = in + (size_t)m * K * V;
  int c  = threadIdx.x & 63;
  int r0 = threadIdx.x >> 6;
#pragma unroll
  for (int i = 0; i < 16; ++i) {
    int r = i * 4 + r0;
    int k = k0 + r, v = v0 + c;
    tile[r][c] = (k < K && v < V) ? src[(size_t)k * V + v] : 0.0f;
  }
  __syncthreads();
  unsigned short* dh = oh + (size_t)m * V * Kp;
  unsigned short* dl = ol + (size_t)m * V * Kp;
#pragma unroll
  for (int i = 0; i < 16; ++i) {
    int r = i * 4 + r0;
    int v = v0 + r, k = k0 + c;
    if (v < V && k < Kp) {
      float val = tile[c][r];
      unsigned short hi = f2bf(val);
      unsigned short lo = f2bf(val - bf2f(hi));
      dh[(size_t)v * Kp + k] = hi;
      dl[(size_t)v * Kp + k] = lo;
    }
  }
}

// =====================================================================
// Fused MLP main kernel.
// Grid: 1600 blocks = 25 n-groups x 64 token-tiles (128 tokens each).
// Block: 512 threads (8 waves), wave tile = 64 tokens x 64 outputs.
// LDS (144 KB dynamic):
//   Ah [128][256] bf16 (64KB)  activation hi, XOR-swizzled
//   Al [128][256] bf16 (64KB)  activation lo
//   Bb [256][32]  bf16 (16KB)  weight K-chunk (staged hi then lo)
// A swizzle: elem(tok,k) = tok*256 + (((k>>3) ^ (tok&31))<<3) + (k&7)
// B swizzle: elem(v,k)   = v*32   + (((k>>3) ^ ((v>>1)&3))<<3) + (k&7)
// =====================================================================
__device__ __forceinline__ void stage_B(const unsigned short* __restrict__ w,
                                        int rowlen, int kbase,
                                        unsigned short* Bb, int tid) {
  int wavebase = (tid >> 6) << 6;
#pragma unroll
  for (int p = 0; p < 2; ++p) {
    int t = tid + p * 512;          // 16B-block id, 0..1023 (16 KB)
    int v = t >> 2, blkp = t & 3;
    int blk = blkp ^ ((v >> 1) & 3);  // inverse-swizzled global source (G21)
    const unsigned short* g = w + (size_t)v * rowlen + kbase + blk * 8;
    unsigned short* ldsb = Bb + (size_t)(wavebase + p * 512) * 8; // wave-uniform
    __builtin_amdgcn_global_load_lds((const __attribute__((address_space(1))) void*)g,
                                     (__attribute__((address_space(3))) void*)ldsb,
                                     16, 0, 0);
  }
}

__global__ __launch_bounds__(512) void mlp_fused(
    const float* __restrict__ x, const float* __restrict__ b0,
    const float* __restrict__ bmid, const float* __restrict__ blast,
    const unsigned short* __restrict__ wt0h, const unsigned short* __restrict__ wt0l,
    const unsigned short* __restrict__ wtmh, const unsigned short* __restrict__ wtml,
    const unsigned short* __restrict__ wtlh, const unsigned short* __restrict__ wtll,
    float* __restrict__ out) {
  extern __shared__ unsigned short smem[];
  unsigned short* Ah = smem;            // 32768 elems
  unsigned short* Al = smem + 32768;    // 32768 elems
  unsigned short* Bb = smem + 65536;    // 8192 elems

  const int tid  = threadIdx.x;
  const int lane = tid & 63;
  const int wave = tid >> 6;
  const int lrow = lane & 15;   // MFMA row/col-within-16
  const int lk   = lane >> 4;   // MFMA k-octet / row-group

  const int g  = blockIdx.x;
  const int n  = g >> 6;         // 0..24  (same-n blocks contiguous -> L2 locality)
  const int t  = g & 63;         // 0..63
  const int bb = t >> 5;         // batch 0..1
  const int s0 = (t & 31) * 128; // seq offset

  const int tg = wave >> 2;      // token group (0..1), 64 rows each
  const int vg = wave & 3;       // v group (0..3), 64 cols each

  // ---- layer 0: stage x (fp32 -> hi/lo bf16) into Ah/Al, k padded to 64 ----
  {
    const float* xp = x + (((size_t)bb * N_ + n) * S_ + s0) * I_;
#pragma unroll
    for (int i = 0; i < 16; ++i) {
      int e = tid + i * 512;      // 0..8191
      int tok = e >> 6, k = e & 63;
      float val = (k < I_) ? xp[tok * I_ + k] : 0.0f;
      unsigned short hi = f2bf(val);
      unsigned short lo = f2bf(val - bf2f(hi));
      int off = tok * 256 + ((((k >> 3) ^ (tok & 31)) << 3) | (k & 7));
      Ah[off] = hi;
      Al[off] = lo;
    }
  }
  __syncthreads();

  f32x4 acc[4][4];

  // ---- layers 0..6 (input layer K=64(pad) + 6 mid layers K=256) ----
#pragma unroll 1
  for (int l = 0; l < 7; ++l) {
    const unsigned short *wh, *wl;
    const float* bias;
    int rowlen, nkc;
    if (l == 0) {
      wh = wt0h + (size_t)n * (W_ * 64);
      wl = wt0l + (size_t)n * (W_ * 64);
      bias = b0 + n * W_;
      rowlen = 64; nkc = 2;
    } else {
      size_t o = ((size_t)(l - 1) * N_ + n) * ((size_t)W_ * W_);
      wh = wtmh + o;
      wl = wtml + o;
      bias = bmid + ((size_t)(l - 1) * N_ + n) * W_;
      rowlen = W_; nkc = 8;
    }
#pragma unroll
    for (int i = 0; i < 4; ++i)
#pragma unroll
      for (int j = 0; j < 4; ++j)
        acc[i][j] = (f32x4){0.f, 0.f, 0.f, 0.f};

#pragma unroll 1
    for (int kc = 0; kc < nkc; ++kc) {
      // ---- phase 1: weight-hi chunk; terms ah*bh + al*bh ----
      stage_B(wh, rowlen, kc * 32, Bb, tid);
      asm volatile("s_waitcnt vmcnt(0)" ::: "memory");
      __syncthreads();

      bf16x8 ahf[4], alf[4];
#pragma unroll
      for (int rt = 0; rt < 4; ++rt) {
        int tok = tg * 64 + rt * 16 + lrow;
        int off = tok * 256 + (((kc * 4 + lk) ^ (tok & 31)) << 3);
        ahf[rt] = *(const bf16x8*)(Ah + off);
        alf[rt] = *(const bf16x8*)(Al + off);
      }
#pragma unroll
      for (int vt = 0; vt < 4; ++vt) {
        int v = vg * 64 + vt * 16 + lrow;
        bf16x8 bf = *(const bf16x8*)(Bb + v * 32 + ((lk ^ ((v >> 1) & 3)) << 3));
#pragma unroll
        for (int rt = 0; rt < 4; ++rt)
          acc[rt][vt] = __builtin_amdgcn_mfma_f32_16x16x32_bf16(ahf[rt], bf, acc[rt][vt], 0, 0, 0);
#pragma unroll
        for (int rt = 0; rt < 4; ++rt)
          acc[rt][vt] = __builtin_amdgcn_mfma_f32_16x16x32_bf16(alf[rt], bf, acc[rt][vt], 0, 0, 0);
      }
      __syncthreads();

      // ---- phase 2: weight-lo chunk; term ah*bl (A frags still in regs) ----
      stage_B(wl, rowlen, kc * 32, Bb, tid);
      asm volatile("s_waitcnt vmcnt(0)" ::: "memory");
      __syncthreads();
#pragma unroll
      for (int vt = 0; vt < 4; ++vt) {
        int v = vg * 64 + vt * 16 + lrow;
        bf16x8 bf = *(const bf16x8*)(Bb + v * 32 + ((lk ^ ((v >> 1) & 3)) << 3));
#pragma unroll
        for (int rt = 0; rt < 4; ++rt)
          acc[rt][vt] = __builtin_amdgcn_mfma_f32_16x16x32_bf16(ahf[rt], bf, acc[rt][vt], 0, 0, 0);
      }
      __syncthreads();
    }

    // ---- epilogue: bias + ReLU + hi/lo split -> Ah/Al (safe: all A reads done) ----
#pragma unroll
    for (int vt = 0; vt < 4; ++vt) {
      int col = vg * 64 + vt * 16 + lrow;
      float bv = bias[col];
#pragma unroll
      for (int rt = 0; rt < 4; ++rt) {
        f32x4 cfr = acc[rt][vt];
#pragma unroll
        for (int r = 0; r < 4; ++r) {
          int tok = tg * 64 + rt * 16 + lk * 4 + r;  // C layout: row=(lane>>4)*4+reg
          float val = fmaxf(cfr[r] + bv, 0.0f);
          unsigned short hi = f2bf(val);
          unsigned short lo = f2bf(val - bf2f(hi));
          int off = tok * 256 + ((((col >> 3) ^ (tok & 31)) << 3) | (col & 7));
          Ah[off] = hi;
          Al[off] = lo;
        }
      }
    }
    __syncthreads();
  }

  // ---- last layer: K=256 -> Z=16, no ReLU, write fp32 out ----
  {
    const unsigned short* wh = wtlh + (size_t)n * (Z_ * W_);
    const unsigned short* wl = wtll + (size_t)n * (Z_ * W_);
    f32x4 accL = (f32x4){0.f, 0.f, 0.f, 0.f};
#pragma unroll 1
    for (int kc = 0; kc < 8; ++kc) {
      if (wave == 0) {  // 1KB hi + 1KB lo, single wave stages both
        int v = lane >> 2, blkp = lane & 3;
        int blk = blkp ^ ((v >> 1) & 3);
        const unsigned short* gh = wh + v * W_ + kc * 32 + blk * 8;
        const unsigned short* gl = wl + v * W_ + kc * 32 + blk * 8;
        __builtin_amdgcn_global_load_lds((const __attribute__((address_space(1))) void*)gh,
                                         (__attribute__((address_space(3))) void*)Bb, 16, 0, 0);
        __builtin_amdgcn_global_load_lds((const __attribute__((address_space(1))) void*)gl,
                                         (__attribute__((address_space(3))) void*)(Bb + 512), 16, 0, 0);
      }
      asm volatile("s_waitcnt vmcnt(0)" ::: "memory");
      __syncthreads();
      int tok = wave * 16 + lrow;
      int aoff = tok * 256 + (((kc * 4 + lk) ^ (tok & 31)) << 3);
      bf16x8 ahf = *(const bf16x8*)(Ah + aoff);
      bf16x8 alf = *(const bf16x8*)(Al + aoff);
      int v = lrow;  // B col = v, 0..15
      int boff = v * 32 + ((lk ^ ((v >> 1) & 3)) << 3);
      bf16x8 bh = *(const bf16x8*)(Bb + boff);
      bf16x8 bl = *(const bf16x8*)(Bb + 512 + boff);
      accL = __builtin_amdgcn_mfma_f32_16x16x32_bf16(ahf, bh, accL, 0, 0, 0);
      accL = __builtin_amdgcn_mfma_f32_16x16x32_bf16(alf, bh, accL, 0, 0, 0);
      accL = __builtin_amdgcn_mfma_f32_16x16x32_bf16(ahf, bl, accL, 0, 0, 0);
      __syncthreads();
    }
    float bv = blast[n * Z_ + lrow];
    float* op = out + (((size_t)bb * N_ + n) * S_ + s0) * Z_;
#pragma unroll
    for (int r = 0; r < 4; ++r) {
      int tok = wave * 16 + lk * 4 + r;
      op[(size_t)tok * Z_ + lrow] = accL[r] + bv;
    }
  }
}

// =====================================================================
// Fallback: pure-fp32 vector-ALU path, no workspace, 64 KB static LDS.
// Correct but slow (~ms). Fires only if ws/attribute opt-in fails.
// Grid: 25 n x 128 tiles of 64 tokens. Block 256: thread v owns column v.
// =====================================================================
__global__ __launch_bounds__(256) void mlp_fallback(
    const float* __restrict__ x, const float* __restrict__ W0,
    const float* __restrict__ b0, const float* __restrict__ Wmid,
    const float* __restrict__ bmid, const float* __restrict__ Wlast,
    const float* __restrict__ blast, float* __restrict__ out) {
  __shared__ float h[64][256];
  const int g  = blockIdx.x;
  const int n  = g >> 7;
  const int t  = g & 127;
  const int bb = t >> 6;
  const int s0 = (t & 63) * 64;
  const int v  = threadIdx.x;

  const float* xp = x + (((size_t)bb * N_ + n) * S_ + s0) * I_;
  float r[64];
  // layer 0
  {
    const float* w = W0 + (size_t)n * I_ * W_;
    float bv = b0[n * W_ + v];
#pragma unroll 8
    for (int i = 0; i < 64; ++i) r[i] = bv;
    for (int k = 0; k < I_; ++k) {
      float wv = w[(size_t)k * W_ + v];
#pragma unroll
      for (int i = 0; i < 64; ++i) r[i] += xp[(size_t)i * I_ + k] * wv;
    }
#pragma unroll
    for (int i = 0; i < 64; ++i) h[i][v] = fmaxf(r[i], 0.f);
    __syncthreads();
  }
  // mid layers
  for (int d = 0; d < D_ - 2; ++d) {
    const float* w = Wmid + ((size_t)d * N_ + n) * W_ * W_;
    float bv = bmid[((size_t)d * N_ + n) * W_ + v];
#pragma unroll 8
    for (int i = 0; i < 64; ++i) r[i] = bv;
    for (int k = 0; k < W_; ++k) {
      float wv = w[(size_t)k * W_ + v];
#pragma unroll
      for (int i = 0; i < 64; ++i) r[i] += h[i][k] * wv;
    }
    __syncthreads();
#pragma unroll
    for (int i = 0; i < 64; ++i) h[i][v] = fmaxf(r[i], 0.f);
    __syncthreads();
  }
  // last layer (threads 0..15 only; no barrier inside)
  if (v < Z_) {
    const float* w = Wlast + (size_t)n * W_ * Z_;
    float bv = blast[n * Z_ + v];
#pragma unroll 8
    for (int i = 0; i < 64; ++i) r[i] = bv;
    for (int k = 0; k < W_; ++k) {
      float wv = w[(size_t)k * Z_ + v];
#pragma unroll
      for (int i = 0; i < 64; ++i) r[i] += h[i][k] * wv;
    }
    float* op = out + (((size_t)bb * N_ + n) * S_ + s0) * Z_;
#pragma unroll
    for (int i = 0; i < 64; ++i) op[(size_t)i * Z_ + v] = r[i];
  }
}

// =====================================================================
extern "C" void kernel_launch(void* const* d_in, const int* in_sizes, int n_in,
                              void* d_out, int out_size, void* d_ws, size_t ws_size,
                              hipStream_t stream) {
  const float* x     = (const float*)d_in[0];
  const float* W0    = (const float*)d_in[1];
  const float* b0    = (const float*)d_in[2];
  const float* Wmid  = (const float*)d_in[3];
  const float* bmid  = (const float*)d_in[4];
  const float* Wlast = (const float*)d_in[5];
  const float* blast = (const float*)d_in[6];
  float* out = (float*)d_out;
  (void)in_sizes; (void)n_in; (void)out_size;

  const size_t n_wt0 = (size_t)N_ * W_ * 64;                 // 409,600
  const size_t n_wtm = (size_t)(D_ - 2) * N_ * W_ * W_;      // 9,830,400
  const size_t n_wtl = (size_t)N_ * Z_ * W_;                 // 102,400
  const size_t need_bytes = 2 * (n_wt0 + n_wtm + n_wtl) * sizeof(unsigned short);

  bool use_main = (ws_size >= need_bytes);
  if (use_main) {
    hipError_t e = hipFuncSetAttribute((const void*)mlp_fused,
                                       hipFuncAttributeMaxDynamicSharedMemorySize,
                                       147456);
    if (e != hipSuccess) use_main = false;
  }

  if (use_main) {
    unsigned short* ws   = (unsigned short*)d_ws;
    unsigned short* wt0h = ws;
    unsigned short* wt0l = wt0h + n_wt0;
    unsigned short* wtmh = wt0l + n_wt0;
    unsigned short* wtml = wtmh + n_wtm;
    unsigned short* wtlh = wtml + n_wtm;
    unsigned short* wtll = wtlh + n_wtl;

    // weight prep every call (ws re-poisoned before every timed launch)
    prep_tr<<<25 * 4, 256, 0, stream>>>(W0, wt0h, wt0l, I_, W_, 64, 1, 4);
    prep_tr<<<150 * 16, 256, 0, stream>>>(Wmid, wtmh, wtml, W_, W_, W_, 4, 4);
    prep_tr<<<25 * 4, 256, 0, stream>>>(Wlast, wtlh, wtll, W_, Z_, W_, 4, 1);

    mlp_fused<<<1600, 512, 147456, stream>>>(x, b0, bmid, blast,
                                             wt0h, wt0l, wtmh, wtml, wtlh, wtll, out);
  } else {
    mlp_fallback<<<25 * 128, 256, 0, stream>>>(x, W0, b0, Wmid, bmid, Wlast, blast, out);
  }
}